// Round 2
// baseline (291.753 us; speedup 1.0000x reference)
//
#include <hip/hip_runtime.h>
#include <hip/hip_bf16.h>

// RelAttnBlock on MI355X (gfx950). I/O is fp32 per the reference dtypes
// (float32 -> const float*); bf16 is used internally for MFMA compute.
// Shapes: B=8, L=1024, EMB=512, H=8, HD=64, BS=1024. M = B*L = 8192.
//
// Pipeline (5 kernels):
//   0) prep: transpose+convert Wq/Wk/Wv/Wo -> wt[4][512][512] bf16 (n-major),
//      convert Er -> er_b bf16 (layout unchanged [h][r][d]).
//   1) LayerNorm x(fp32) -> h (bf16, 8192x512). 1 wave/row.
//   2) QKV GEMM (bf16 MFMA): h @ W{q,k,v} + b. K pre-scaled by HD^-0.5.
//      Outputs per-head: q[bh][l][d], k'[bh][l][d], vT[bh][d][l] (all bf16).
//   3) Attention per (b,h), flash online-softmax, 64-row Q tiles.
//      Rel bias: 64x128 rect MFMA cover of the (l, (k-l) mod L) parallelogram,
//      gathered from LDS at col = 63 + dk - dl.
//   4) Out GEMM: O @ Wo + bo -> d_out (fp32).
//
// ws layout (bytes): wt 0..2MB | er_b 2..3MB | h/o_ws 3..11MB (aliased)
//                    q 11..19MB | k 19..27MB | vT 27..35MB.

typedef __bf16 bf16;
typedef __bf16 bf16x8 __attribute__((ext_vector_type(8)));
typedef float floatx4 __attribute__((ext_vector_type(4)));
typedef float f32x4 __attribute__((ext_vector_type(4)));

#define MFMA16 __builtin_amdgcn_mfma_f32_16x16x32_bf16

__global__ __launch_bounds__(256) void prep_kernel(
    const float* __restrict__ Wq, const float* __restrict__ Wk,
    const float* __restrict__ Wv, const float* __restrict__ Wo,
    const float* __restrict__ Er,
    bf16* __restrict__ wt, bf16* __restrict__ er_b) {
  int idx = blockIdx.x * 256 + threadIdx.x;
  if (idx < 4 * 512 * 512) {
    int w = idx >> 18;
    int r = idx & 262143;
    int n = r >> 9, k = r & 511;
    const float* W = (w == 0) ? Wq : (w == 1) ? Wk : (w == 2) ? Wv : Wo;
    wt[idx] = (bf16)W[k * 512 + n];              // wt[w][n][k] = W[k][n]
  } else {
    int e = idx - 4 * 512 * 512;                 // 0..524287 = 8*1024*64
    er_b[e] = (bf16)Er[e];
  }
}

__global__ __launch_bounds__(256) void ln_kernel(
    const float* __restrict__ x, const float* __restrict__ g,
    const float* __restrict__ bvec, bf16* __restrict__ h) {
  int row = blockIdx.x * 4 + (threadIdx.x >> 6);   // 8192 rows
  int lane = threadIdx.x & 63;
  const f32x4* xr = (const f32x4*)(x + row * 512 + lane * 8);
  f32x4 v0 = xr[0], v1 = xr[1];
  float f[8];
  f[0] = v0[0]; f[1] = v0[1]; f[2] = v0[2]; f[3] = v0[3];
  f[4] = v1[0]; f[5] = v1[1]; f[6] = v1[2]; f[7] = v1[3];
  float s = 0.f, ss = 0.f;
#pragma unroll
  for (int i = 0; i < 8; i++) { s += f[i]; ss += f[i] * f[i]; }
#pragma unroll
  for (int m = 1; m < 64; m <<= 1) { s += __shfl_xor(s, m); ss += __shfl_xor(ss, m); }
  float mean = s * (1.0f / 512.0f);
  float var = ss * (1.0f / 512.0f) - mean * mean;
  float inv = rsqrtf(var + 1e-5f);
  const f32x4* gr = (const f32x4*)(g + lane * 8);
  const f32x4* br = (const f32x4*)(bvec + lane * 8);
  f32x4 g0 = gr[0], g1 = gr[1], b0 = br[0], b1 = br[1];
  float gg[8], bb[8];
  gg[0] = g0[0]; gg[1] = g0[1]; gg[2] = g0[2]; gg[3] = g0[3];
  gg[4] = g1[0]; gg[5] = g1[1]; gg[6] = g1[2]; gg[7] = g1[3];
  bb[0] = b0[0]; bb[1] = b0[1]; bb[2] = b0[2]; bb[3] = b0[3];
  bb[4] = b1[0]; bb[5] = b1[1]; bb[6] = b1[2]; bb[7] = b1[3];
  bf16x8 o;
#pragma unroll
  for (int i = 0; i < 8; i++)
    o[i] = (bf16)((f[i] - mean) * inv * gg[i] + bb[i]);
  *(bf16x8*)(h + row * 512 + lane * 8) = o;
}

// C/D layout (m89-verified): col = lane&15, row = (lane>>4)*4 + reg.
// A layout: m = lane&15, k = (lane>>4)*8 + j.  B layout: n = lane&15, k likewise.

__global__ __launch_bounds__(256) void qkv_gemm(
    const bf16* __restrict__ A,      // h: 8192 x 512
    const bf16* __restrict__ wt,     // [3][512][512] n-major
    const float* __restrict__ bq, const float* __restrict__ bk,
    const float* __restrict__ bv,
    bf16* __restrict__ q_ws, bf16* __restrict__ k_ws, bf16* __restrict__ vt_ws) {
  __shared__ __align__(16) bf16 As[64 * 32];
  __shared__ __align__(16) bf16 Bs[64 * 32];
  int m0 = blockIdx.x * 64;
  int ng0 = blockIdx.y * 64;          // 0..1535
  int w = ng0 >> 9;                   // 0=Q 1=K 2=V (uniform per block)
  int n0 = ng0 & 511;
  const bf16* Bt = wt + (w << 18);
  int tid = threadIdx.x;
  int wave = tid >> 6, lane = tid & 63, quad = lane >> 4, l16 = lane & 15;

  floatx4 acc[4] = {};
  for (int k0 = 0; k0 < 512; k0 += 32) {
    int r = tid >> 2, c = (tid & 3) * 8;
    *(bf16x8*)(As + r * 32 + c) = *(const bf16x8*)(A + (m0 + r) * 512 + k0 + c);
    *(bf16x8*)(Bs + r * 32 + c) = *(const bf16x8*)(Bt + (n0 + r) * 512 + k0 + c);
    __syncthreads();
    bf16x8 a = *(const bf16x8*)(As + (wave * 16 + l16) * 32 + quad * 8);
#pragma unroll
    for (int nt = 0; nt < 4; nt++) {
      bf16x8 b = *(const bf16x8*)(Bs + (nt * 16 + l16) * 32 + quad * 8);
      acc[nt] = MFMA16(a, b, acc[nt], 0, 0, 0);
    }
    __syncthreads();
  }

  const float* bias = (w == 0) ? bq : (w == 1) ? bk : bv;
#pragma unroll
  for (int nt = 0; nt < 4; nt++) {
    int col = n0 + nt * 16 + l16;     // 0..511 within this W
    float bb = bias[col];
    int hh = col >> 6, d = col & 63;
#pragma unroll
    for (int r = 0; r < 4; r++) {
      int mrow = m0 + wave * 16 + quad * 4 + r;   // 0..8191
      int b_ = mrow >> 10, l = mrow & 1023;
      int bh = b_ * 8 + hh;
      float v = acc[nt][r] + bb;
      if (w == 0)       q_ws[(bh << 16) + (l << 6) + d] = (bf16)v;
      else if (w == 1)  k_ws[(bh << 16) + (l << 6) + d] = (bf16)(v * 0.125f);
      else              vt_ws[(bh << 16) + (d << 10) + l] = (bf16)v;
    }
  }
}

__global__ __launch_bounds__(256) void attn_kernel(
    const bf16* __restrict__ q_ws, const bf16* __restrict__ k_ws,
    const bf16* __restrict__ vt_ws, const bf16* __restrict__ Er,
    bf16* __restrict__ o_ws) {
  __shared__ __align__(16) bf16 Ks[64 * 64];          // [key][d]      8KB
  __shared__ __align__(16) bf16 Ers[128 * 64];        // [cover r][d] 16KB
  __shared__ __align__(16) bf16 Vs[64 * 64];          // [d][key]      8KB
  __shared__ __align__(16) float bias_s[4][16 * 128]; // per-wave     32KB
  __shared__ __align__(16) bf16 Ps[4][16 * 64];       // per-wave      8KB

  int qt = blockIdx.x;       // 0..15
  int bh = blockIdx.y;       // 0..63
  int hh = bh & 7;
  int l0 = qt * 64;
  int tid = threadIdx.x, wave = tid >> 6, lane = tid & 63;
  int quad = lane >> 4, l16 = lane & 15;

  // Persistent Q A-fragments for this wave's 16-row strip (d = 0..31, 32..63).
  const bf16* qbase = q_ws + (bh << 16) + ((l0 + wave * 16 + l16) << 6);
  bf16x8 aq0 = *(const bf16x8*)(qbase + quad * 8);
  bf16x8 aq1 = *(const bf16x8*)(qbase + 32 + quad * 8);

  float m_run[4], l_run[4];
  floatx4 acc_o[4] = {};
#pragma unroll
  for (int r = 0; r < 4; r++) { m_run[r] = -1e30f; l_run[r] = 0.f; }

  for (int kt = 0; kt < 16; kt++) {
    int k0 = kt * 64;
    // ---- stage K', V^T, Er cover ----
    {
      int r = tid >> 2, c = (tid & 3) << 4;
      const bf16* ksrc = k_ws + (bh << 16) + ((k0 + r) << 6) + c;
      *(bf16x8*)(Ks + r * 64 + c) = *(const bf16x8*)ksrc;
      *(bf16x8*)(Ks + r * 64 + c + 8) = *(const bf16x8*)(ksrc + 8);
      const bf16* vsrc = vt_ws + (bh << 16) + (r << 10) + k0 + c;
      *(bf16x8*)(Vs + r * 64 + c) = *(const bf16x8*)vsrc;
      *(bf16x8*)(Vs + r * 64 + c + 8) = *(const bf16x8*)(vsrc + 8);
      int er_r = tid >> 1, er_c = (tid & 1) << 5;
      int base = k0 - l0 - 63;
      int grow = (base + er_r + 2048) & 1023;        // wrap mod 1024
      const bf16* esrc = Er + (hh << 16) + (grow << 6) + er_c;
      bf16* edst = Ers + er_r * 64 + er_c;
      *(bf16x8*)(edst) = *(const bf16x8*)(esrc);
      *(bf16x8*)(edst + 8) = *(const bf16x8*)(esrc + 8);
      *(bf16x8*)(edst + 16) = *(const bf16x8*)(esrc + 16);
      *(bf16x8*)(edst + 24) = *(const bf16x8*)(esrc + 24);
    }
    __syncthreads();

    // ---- S = Q K'^T (scale already folded into K') ----
    floatx4 acc_s[4] = {};
#pragma unroll
    for (int nt = 0; nt < 4; nt++) {
      bf16x8 b0 = *(const bf16x8*)(Ks + (nt * 16 + l16) * 64 + quad * 8);
      bf16x8 b1 = *(const bf16x8*)(Ks + (nt * 16 + l16) * 64 + 32 + quad * 8);
      acc_s[nt] = MFMA16(aq0, b0, acc_s[nt], 0, 0, 0);
      acc_s[nt] = MFMA16(aq1, b1, acc_s[nt], 0, 0, 0);
    }
    // ---- rel-bias rect tile: bias[l][c] = Q[l] . Er[(base+c) mod 1024] ----
#pragma unroll
    for (int nt = 0; nt < 8; nt++) {
      bf16x8 b0 = *(const bf16x8*)(Ers + (nt * 16 + l16) * 64 + quad * 8);
      bf16x8 b1 = *(const bf16x8*)(Ers + (nt * 16 + l16) * 64 + 32 + quad * 8);
      floatx4 accb = {};
      accb = MFMA16(aq0, b0, accb, 0, 0, 0);
      accb = MFMA16(aq1, b1, accb, 0, 0, 0);
#pragma unroll
      for (int r = 0; r < 4; r++)
        bias_s[wave][(quad * 4 + r) * 128 + nt * 16 + l16] = accb[r];
    }
    __syncthreads();

    // ---- gather bias (col = 63 + dk - full-tile dl), online softmax ----
    float sv[4][4];
#pragma unroll
    for (int nt = 0; nt < 4; nt++) {
      int dk = nt * 16 + l16;
#pragma unroll
      for (int r = 0; r < 4; r++) {
        int sdl = quad * 4 + r;                       // strip-local row
        int c = 63 + dk - wave * 16 - sdl;            // 0..126
        sv[nt][r] = acc_s[nt][r] + bias_s[wave][sdl * 128 + c];
      }
    }
#pragma unroll
    for (int r = 0; r < 4; r++) {
      float mx = fmaxf(fmaxf(sv[0][r], sv[1][r]), fmaxf(sv[2][r], sv[3][r]));
#pragma unroll
      for (int m = 1; m < 16; m <<= 1) mx = fmaxf(mx, __shfl_xor(mx, m));
      float m_new = fmaxf(m_run[r], mx);
      float alpha = __expf(m_run[r] - m_new);
      float rs = 0.f;
#pragma unroll
      for (int nt = 0; nt < 4; nt++) {
        float p = __expf(sv[nt][r] - m_new);
        sv[nt][r] = p;
        rs += p;
      }
#pragma unroll
      for (int m = 1; m < 16; m <<= 1) rs += __shfl_xor(rs, m);
      l_run[r] = l_run[r] * alpha + rs;
      m_run[r] = m_new;
      acc_o[0][r] *= alpha; acc_o[1][r] *= alpha;
      acc_o[2][r] *= alpha; acc_o[3][r] *= alpha;
    }
    // ---- P: C-layout -> LDS -> A-layout ----
#pragma unroll
    for (int nt = 0; nt < 4; nt++)
#pragma unroll
      for (int r = 0; r < 4; r++)
        Ps[wave][(quad * 4 + r) * 64 + nt * 16 + l16] = (bf16)sv[nt][r];
    __syncthreads();

    bf16x8 ap0 = *(const bf16x8*)(&Ps[wave][l16 * 64 + quad * 8]);
    bf16x8 ap1 = *(const bf16x8*)(&Ps[wave][l16 * 64 + 32 + quad * 8]);
#pragma unroll
    for (int dt = 0; dt < 4; dt++) {
      bf16x8 b0 = *(const bf16x8*)(Vs + (dt * 16 + l16) * 64 + quad * 8);
      bf16x8 b1 = *(const bf16x8*)(Vs + (dt * 16 + l16) * 64 + 32 + quad * 8);
      acc_o[dt] = MFMA16(ap0, b0, acc_o[dt], 0, 0, 0);
      acc_o[dt] = MFMA16(ap1, b1, acc_o[dt], 0, 0, 0);
    }
    __syncthreads();
  }

  float invl[4];
#pragma unroll
  for (int r = 0; r < 4; r++) invl[r] = 1.0f / l_run[r];
#pragma unroll
  for (int dt = 0; dt < 4; dt++) {
    int col = (hh << 6) + dt * 16 + l16;              // h*64 + d
#pragma unroll
    for (int r = 0; r < 4; r++) {
      int row = ((bh >> 3) << 10) + l0 + wave * 16 + quad * 4 + r;  // b*1024 + l
      o_ws[row * 512 + col] = (bf16)(acc_o[dt][r] * invl[r]);
    }
  }
}

__global__ __launch_bounds__(256) void out_gemm(
    const bf16* __restrict__ A,      // o_ws: 8192 x 512
    const bf16* __restrict__ Bt,     // WoT: [512][512] n-major
    const float* __restrict__ bo, float* __restrict__ out) {
  __shared__ __align__(16) bf16 As[64 * 32];
  __shared__ __align__(16) bf16 Bs[64 * 32];
  int m0 = blockIdx.x * 64;
  int n0 = blockIdx.y * 64;
  int tid = threadIdx.x;
  int wave = tid >> 6, lane = tid & 63, quad = lane >> 4, l16 = lane & 15;

  floatx4 acc[4] = {};
  for (int k0 = 0; k0 < 512; k0 += 32) {
    int r = tid >> 2, c = (tid & 3) * 8;
    *(bf16x8*)(As + r * 32 + c) = *(const bf16x8*)(A + (m0 + r) * 512 + k0 + c);
    *(bf16x8*)(Bs + r * 32 + c) = *(const bf16x8*)(Bt + (n0 + r) * 512 + k0 + c);
    __syncthreads();
    bf16x8 a = *(const bf16x8*)(As + (wave * 16 + l16) * 32 + quad * 8);
#pragma unroll
    for (int nt = 0; nt < 4; nt++) {
      bf16x8 b = *(const bf16x8*)(Bs + (nt * 16 + l16) * 32 + quad * 8);
      acc[nt] = MFMA16(a, b, acc[nt], 0, 0, 0);
    }
    __syncthreads();
  }
#pragma unroll
  for (int nt = 0; nt < 4; nt++) {
    int col = n0 + nt * 16 + l16;
    float bb = bo[col];
#pragma unroll
    for (int r = 0; r < 4; r++) {
      int mrow = m0 + wave * 16 + quad * 4 + r;
      out[mrow * 512 + col] = acc[nt][r] + bb;
    }
  }
}

extern "C" void kernel_launch(void* const* d_in, const int* in_sizes, int n_in,
                              void* d_out, int out_size, void* d_ws, size_t ws_size,
                              hipStream_t stream) {
  const float* x    = (const float*)d_in[0];
  const float* ln_g = (const float*)d_in[1];
  const float* ln_b = (const float*)d_in[2];
  const float* Wq   = (const float*)d_in[3];
  const float* bq   = (const float*)d_in[4];
  const float* Wk   = (const float*)d_in[5];
  const float* bk   = (const float*)d_in[6];
  const float* Wv   = (const float*)d_in[7];
  const float* bv   = (const float*)d_in[8];
  const float* Wo   = (const float*)d_in[9];
  const float* bo   = (const float*)d_in[10];
  const float* Er   = (const float*)d_in[11];
  float* out = (float*)d_out;

  char* ws = (char*)d_ws;
  bf16* wt    = (bf16*)(ws);                       // 2MB: [4][512][512]
  bf16* er_b  = (bf16*)(ws + (2u << 20));          // 1MB: [8][1024][64]
  bf16* h     = (bf16*)(ws + (3u << 20));          // 8MB
  bf16* o_ws  = h;                                 // alias (h dead by then)
  bf16* q_ws  = (bf16*)(ws + (11u << 20));         // 8MB
  bf16* k_ws  = (bf16*)(ws + (19u << 20));         // 8MB
  bf16* vt_ws = (bf16*)(ws + (27u << 20));         // 8MB, ends at 35MB

  prep_kernel<<<6144, 256, 0, stream>>>(Wq, Wk, Wv, Wo, Er, wt, er_b);
  ln_kernel<<<2048, 256, 0, stream>>>(x, ln_g, ln_b, h);
  qkv_gemm<<<dim3(128, 24), 256, 0, stream>>>(h, wt, bq, bk, bv, q_ws, k_ws, vt_ws);
  attn_kernel<<<dim3(16, 64), 256, 0, stream>>>(q_ws, k_ws, vt_ws, er_b, o_ws);
  out_gemm<<<dim3(128, 8), 256, 0, stream>>>(o_ws, wt + 3 * 262144, bo, out);
}

// Round 3
// 243.574 us; speedup vs baseline: 1.1978x; 1.1978x over previous
//
#include <hip/hip_runtime.h>
#include <hip/hip_bf16.h>

// RelAttnBlock on MI355X (gfx950). fp32 I/O, bf16 MFMA core.
// B=8, L=1024, EMB=512, H=8, HD=64, BS=1024, M=8192.
//
// R3: LDS bank-conflict padding (stride 72 bf16 / 84 f32 / 40 bf16 GEMM),
//     per-wave 5-tile rel-bias cover (cols 15+dk-sdl local), 2 barriers/kt
//     instead of 4 (bias_s/Ps are wave-private; DS in-order per wave),
//     prep+ln merged into one dispatch.

typedef __bf16 bf16;
typedef __bf16 bf16x8 __attribute__((ext_vector_type(8)));
typedef float floatx4 __attribute__((ext_vector_type(4)));
typedef float f32x4 __attribute__((ext_vector_type(4)));

#define MFMA16 __builtin_amdgcn_mfma_f32_16x16x32_bf16

#define KS 72   // padded stride for 64-col bf16 tiles (144B = 4-bank rotation)
#define BS_ 84  // padded stride for bias_s (f32)
#define GS 40   // padded stride for 32-col bf16 GEMM tiles

// ---- prep (weights transpose+cvt, Er cvt) + LayerNorm, one dispatch ----
__global__ __launch_bounds__(256) void prep_ln_kernel(
    const float* __restrict__ Wq, const float* __restrict__ Wk,
    const float* __restrict__ Wv, const float* __restrict__ Wo,
    const float* __restrict__ Er,
    const float* __restrict__ x, const float* __restrict__ g,
    const float* __restrict__ bvec,
    bf16* __restrict__ wt, bf16* __restrict__ er_b, bf16* __restrict__ h) {
  int blk = blockIdx.x;
  if (blk < 6144) {
    int idx = blk * 256 + threadIdx.x;
    if (idx < 4 * 512 * 512) {
      int w = idx >> 18;
      int r = idx & 262143;
      int n = r >> 9, k = r & 511;
      const float* W = (w == 0) ? Wq : (w == 1) ? Wk : (w == 2) ? Wv : Wo;
      wt[idx] = (bf16)W[k * 512 + n];            // wt[w][n][k] = W[k][n]
    } else {
      int e = idx - 4 * 512 * 512;               // 8*1024*64
      er_b[e] = (bf16)Er[e];
    }
    return;
  }
  int row = (blk - 6144) * 4 + (threadIdx.x >> 6);   // 8192 rows
  int lane = threadIdx.x & 63;
  const f32x4* xr = (const f32x4*)(x + row * 512 + lane * 8);
  f32x4 v0 = xr[0], v1 = xr[1];
  float f[8] = {v0[0], v0[1], v0[2], v0[3], v1[0], v1[1], v1[2], v1[3]};
  float s = 0.f, ss = 0.f;
#pragma unroll
  for (int i = 0; i < 8; i++) { s += f[i]; ss += f[i] * f[i]; }
#pragma unroll
  for (int m = 1; m < 64; m <<= 1) { s += __shfl_xor(s, m); ss += __shfl_xor(ss, m); }
  float mean = s * (1.0f / 512.0f);
  float var = ss * (1.0f / 512.0f) - mean * mean;
  float inv = rsqrtf(var + 1e-5f);
  const f32x4* gr = (const f32x4*)(g + lane * 8);
  const f32x4* br = (const f32x4*)(bvec + lane * 8);
  f32x4 g0 = gr[0], g1 = gr[1], b0 = br[0], b1 = br[1];
  float gg[8] = {g0[0], g0[1], g0[2], g0[3], g1[0], g1[1], g1[2], g1[3]};
  float bb[8] = {b0[0], b0[1], b0[2], b0[3], b1[0], b1[1], b1[2], b1[3]};
  bf16x8 o;
#pragma unroll
  for (int i = 0; i < 8; i++)
    o[i] = (bf16)((f[i] - mean) * inv * gg[i] + bb[i]);
  *(bf16x8*)(h + row * 512 + lane * 8) = o;
}

// C/D layout: col = lane&15, row = (lane>>4)*4 + reg.
// A layout: m = lane&15, k = (lane>>4)*8 + j.  B layout: n = lane&15, same k.

__global__ __launch_bounds__(256) void qkv_gemm(
    const bf16* __restrict__ A,      // h: 8192 x 512
    const bf16* __restrict__ wt,     // [3][512][512] n-major
    const float* __restrict__ bq, const float* __restrict__ bk,
    const float* __restrict__ bv,
    bf16* __restrict__ q_ws, bf16* __restrict__ k_ws, bf16* __restrict__ vt_ws) {
  __shared__ __align__(16) bf16 As[64 * GS];
  __shared__ __align__(16) bf16 Bs[64 * GS];
  int m0 = blockIdx.x * 64;
  int ng0 = blockIdx.y * 64;          // 0..1535
  int w = ng0 >> 9;                   // 0=Q 1=K 2=V
  int n0 = ng0 & 511;
  const bf16* Bt = wt + (w << 18);
  int tid = threadIdx.x;
  int wave = tid >> 6, lane = tid & 63, quad = lane >> 4, l16 = lane & 15;

  floatx4 acc[4] = {};
  for (int k0 = 0; k0 < 512; k0 += 32) {
    int r = tid >> 2, c = (tid & 3) * 8;
    *(bf16x8*)(As + r * GS + c) = *(const bf16x8*)(A + (m0 + r) * 512 + k0 + c);
    *(bf16x8*)(Bs + r * GS + c) = *(const bf16x8*)(Bt + (n0 + r) * 512 + k0 + c);
    __syncthreads();
    bf16x8 a = *(const bf16x8*)(As + (wave * 16 + l16) * GS + quad * 8);
#pragma unroll
    for (int nt = 0; nt < 4; nt++) {
      bf16x8 b = *(const bf16x8*)(Bs + (nt * 16 + l16) * GS + quad * 8);
      acc[nt] = MFMA16(a, b, acc[nt], 0, 0, 0);
    }
    __syncthreads();
  }

  const float* bias = (w == 0) ? bq : (w == 1) ? bk : bv;
#pragma unroll
  for (int nt = 0; nt < 4; nt++) {
    int col = n0 + nt * 16 + l16;
    float bb = bias[col];
    int hh = col >> 6, d = col & 63;
#pragma unroll
    for (int r = 0; r < 4; r++) {
      int mrow = m0 + wave * 16 + quad * 4 + r;
      int b_ = mrow >> 10, l = mrow & 1023;
      int bh = b_ * 8 + hh;
      float v = acc[nt][r] + bb;
      if (w == 0)       q_ws[(bh << 16) + (l << 6) + d] = (bf16)v;
      else if (w == 1)  k_ws[(bh << 16) + (l << 6) + d] = (bf16)(v * 0.125f);
      else              vt_ws[(bh << 16) + (d << 10) + l] = (bf16)v;
    }
  }
}

__global__ __launch_bounds__(256) void attn_kernel(
    const bf16* __restrict__ q_ws, const bf16* __restrict__ k_ws,
    const bf16* __restrict__ vt_ws, const bf16* __restrict__ Er,
    bf16* __restrict__ o_ws) {
  __shared__ __align__(16) bf16 Ks_s[64 * KS];           // [key][d]
  __shared__ __align__(16) bf16 Ers[128 * KS];           // [cover r][d]
  __shared__ __align__(16) bf16 Vs[64 * KS];             // [d][key]
  __shared__ __align__(16) float bias_s[4][16 * BS_];    // per-wave 16x80(+4)
  __shared__ __align__(16) bf16 Ps[4][16 * KS];          // per-wave

  int qt = blockIdx.x;       // 0..15
  int bh = blockIdx.y;       // 0..63
  int hh = bh & 7;
  int l0 = qt * 64;
  int tid = threadIdx.x, wave = tid >> 6, lane = tid & 63;
  int quad = lane >> 4, l16 = lane & 15;

  // Persistent Q A-fragments for this wave's 16-row strip.
  const bf16* qbase = q_ws + (bh << 16) + ((l0 + wave * 16 + l16) << 6);
  bf16x8 aq0 = *(const bf16x8*)(qbase + quad * 8);
  bf16x8 aq1 = *(const bf16x8*)(qbase + 32 + quad * 8);

  float m_run[4], l_run[4];
  floatx4 acc_o[4] = {};
#pragma unroll
  for (int r = 0; r < 4; r++) { m_run[r] = -1e30f; l_run[r] = 0.f; }

  for (int kt = 0; kt < 16; kt++) {
    int k0 = kt * 64;
    // ---- stage K', V^T, Er cover ----
    {
      int r = tid >> 2, c = (tid & 3) << 4;
      const bf16* ksrc = k_ws + (bh << 16) + ((k0 + r) << 6) + c;
      *(bf16x8*)(Ks_s + r * KS + c) = *(const bf16x8*)ksrc;
      *(bf16x8*)(Ks_s + r * KS + c + 8) = *(const bf16x8*)(ksrc + 8);
      const bf16* vsrc = vt_ws + (bh << 16) + (r << 10) + k0 + c;
      *(bf16x8*)(Vs + r * KS + c) = *(const bf16x8*)vsrc;
      *(bf16x8*)(Vs + r * KS + c + 8) = *(const bf16x8*)(vsrc + 8);
      int er_r = tid >> 1, er_c = (tid & 1) << 5;
      int base = k0 - l0 - 63;
      int grow = (base + er_r + 2048) & 1023;        // wrap mod 1024
      const bf16* esrc = Er + (hh << 16) + (grow << 6) + er_c;
      bf16* edst = Ers + er_r * KS + er_c;
      *(bf16x8*)(edst) = *(const bf16x8*)(esrc);
      *(bf16x8*)(edst + 8) = *(const bf16x8*)(esrc + 8);
      *(bf16x8*)(edst + 16) = *(const bf16x8*)(esrc + 16);
      *(bf16x8*)(edst + 24) = *(const bf16x8*)(esrc + 24);
    }
    __syncthreads();

    // ---- S = Q K'^T ----
    floatx4 acc_s[4] = {};
#pragma unroll
    for (int nt = 0; nt < 4; nt++) {
      bf16x8 b0 = *(const bf16x8*)(Ks_s + (nt * 16 + l16) * KS + quad * 8);
      bf16x8 b1 = *(const bf16x8*)(Ks_s + (nt * 16 + l16) * KS + 32 + quad * 8);
      acc_s[nt] = MFMA16(aq0, b0, acc_s[nt], 0, 0, 0);
      acc_s[nt] = MFMA16(aq1, b1, acc_s[nt], 0, 0, 0);
    }
    // ---- rel-bias: 5-tile per-wave cover. Wave w needs global cols
    //      [48-16w, 126-16w] => tiles nt = 3-w .. 7-w; local col = g - 48+16w.
#pragma unroll
    for (int nt2 = 0; nt2 < 5; nt2++) {
      int nt = nt2 + 3 - wave;
      bf16x8 b0 = *(const bf16x8*)(Ers + (nt * 16 + l16) * KS + quad * 8);
      bf16x8 b1 = *(const bf16x8*)(Ers + (nt * 16 + l16) * KS + 32 + quad * 8);
      floatx4 accb = {};
      accb = MFMA16(aq0, b0, accb, 0, 0, 0);
      accb = MFMA16(aq1, b1, accb, 0, 0, 0);
#pragma unroll
      for (int r = 0; r < 4; r++)
        bias_s[wave][(quad * 4 + r) * BS_ + nt2 * 16 + l16] = accb[r];
    }
    // (no barrier: bias_s[wave] is wave-private; DS ops in-order per wave)

    // ---- gather bias (local col = 15 + dk - sdl), online softmax ----
    float sv[4][4];
#pragma unroll
    for (int nt = 0; nt < 4; nt++) {
      int dk = nt * 16 + l16;
#pragma unroll
      for (int r = 0; r < 4; r++) {
        int sdl = quad * 4 + r;
        sv[nt][r] = acc_s[nt][r] + bias_s[wave][sdl * BS_ + 15 + dk - sdl];
      }
    }
#pragma unroll
    for (int r = 0; r < 4; r++) {
      float mx = fmaxf(fmaxf(sv[0][r], sv[1][r]), fmaxf(sv[2][r], sv[3][r]));
#pragma unroll
      for (int m = 1; m < 16; m <<= 1) mx = fmaxf(mx, __shfl_xor(mx, m));
      float m_new = fmaxf(m_run[r], mx);
      float alpha = __expf(m_run[r] - m_new);
      float rs = 0.f;
#pragma unroll
      for (int nt = 0; nt < 4; nt++) {
        float p = __expf(sv[nt][r] - m_new);
        sv[nt][r] = p;
        rs += p;
      }
#pragma unroll
      for (int m = 1; m < 16; m <<= 1) rs += __shfl_xor(rs, m);
      l_run[r] = l_run[r] * alpha + rs;
      m_run[r] = m_new;
      acc_o[0][r] *= alpha; acc_o[1][r] *= alpha;
      acc_o[2][r] *= alpha; acc_o[3][r] *= alpha;
    }
    // ---- P: C-layout -> LDS -> A-layout (wave-private, no barrier) ----
#pragma unroll
    for (int nt = 0; nt < 4; nt++)
#pragma unroll
      for (int r = 0; r < 4; r++)
        Ps[wave][(quad * 4 + r) * KS + nt * 16 + l16] = (bf16)sv[nt][r];

    bf16x8 ap0 = *(const bf16x8*)(&Ps[wave][l16 * KS + quad * 8]);
    bf16x8 ap1 = *(const bf16x8*)(&Ps[wave][l16 * KS + 32 + quad * 8]);
#pragma unroll
    for (int dt = 0; dt < 4; dt++) {
      bf16x8 b0 = *(const bf16x8*)(Vs + (dt * 16 + l16) * KS + quad * 8);
      bf16x8 b1 = *(const bf16x8*)(Vs + (dt * 16 + l16) * KS + 32 + quad * 8);
      acc_o[dt] = MFMA16(ap0, b0, acc_o[dt], 0, 0, 0);
      acc_o[dt] = MFMA16(ap1, b1, acc_o[dt], 0, 0, 0);
    }
    __syncthreads();   // protect Ks/Ers/Vs restage next kt
  }

  float invl[4];
#pragma unroll
  for (int r = 0; r < 4; r++) invl[r] = 1.0f / l_run[r];
#pragma unroll
  for (int dt = 0; dt < 4; dt++) {
    int col = (hh << 6) + dt * 16 + l16;
#pragma unroll
    for (int r = 0; r < 4; r++) {
      int row = ((bh >> 3) << 10) + l0 + wave * 16 + quad * 4 + r;
      o_ws[row * 512 + col] = (bf16)(acc_o[dt][r] * invl[r]);
    }
  }
}

__global__ __launch_bounds__(256) void out_gemm(
    const bf16* __restrict__ A,      // o_ws: 8192 x 512
    const bf16* __restrict__ Bt,     // WoT n-major
    const float* __restrict__ bo, float* __restrict__ out) {
  __shared__ __align__(16) bf16 As[64 * GS];
  __shared__ __align__(16) bf16 Bs[64 * GS];
  int m0 = blockIdx.x * 64;
  int n0 = blockIdx.y * 64;
  int tid = threadIdx.x;
  int wave = tid >> 6, lane = tid & 63, quad = lane >> 4, l16 = lane & 15;

  floatx4 acc[4] = {};
  for (int k0 = 0; k0 < 512; k0 += 32) {
    int r = tid >> 2, c = (tid & 3) * 8;
    *(bf16x8*)(As + r * GS + c) = *(const bf16x8*)(A + (m0 + r) * 512 + k0 + c);
    *(bf16x8*)(Bs + r * GS + c) = *(const bf16x8*)(Bt + (n0 + r) * 512 + k0 + c);
    __syncthreads();
    bf16x8 a = *(const bf16x8*)(As + (wave * 16 + l16) * GS + quad * 8);
#pragma unroll
    for (int nt = 0; nt < 4; nt++) {
      bf16x8 b = *(const bf16x8*)(Bs + (nt * 16 + l16) * GS + quad * 8);
      acc[nt] = MFMA16(a, b, acc[nt], 0, 0, 0);
    }
    __syncthreads();
  }
#pragma unroll
  for (int nt = 0; nt < 4; nt++) {
    int col = n0 + nt * 16 + l16;
    float bb = bo[col];
#pragma unroll
    for (int r = 0; r < 4; r++) {
      int mrow = m0 + wave * 16 + quad * 4 + r;
      out[mrow * 512 + col] = acc[nt][r] + bb;
    }
  }
}

extern "C" void kernel_launch(void* const* d_in, const int* in_sizes, int n_in,
                              void* d_out, int out_size, void* d_ws, size_t ws_size,
                              hipStream_t stream) {
  const float* x    = (const float*)d_in[0];
  const float* ln_g = (const float*)d_in[1];
  const float* ln_b = (const float*)d_in[2];
  const float* Wq   = (const float*)d_in[3];
  const float* bq   = (const float*)d_in[4];
  const float* Wk   = (const float*)d_in[5];
  const float* bk   = (const float*)d_in[6];
  const float* Wv   = (const float*)d_in[7];
  const float* bv   = (const float*)d_in[8];
  const float* Wo   = (const float*)d_in[9];
  const float* bo   = (const float*)d_in[10];
  const float* Er   = (const float*)d_in[11];
  float* out = (float*)d_out;

  char* ws = (char*)d_ws;
  bf16* wt    = (bf16*)(ws);                       // 2MB: [4][512][512]
  bf16* er_b  = (bf16*)(ws + (2u << 20));          // 1MB
  bf16* h     = (bf16*)(ws + (3u << 20));          // 8MB
  bf16* o_ws  = h;                                 // alias
  bf16* q_ws  = (bf16*)(ws + (11u << 20));         // 8MB
  bf16* k_ws  = (bf16*)(ws + (19u << 20));         // 8MB
  bf16* vt_ws = (bf16*)(ws + (27u << 20));         // 8MB

  prep_ln_kernel<<<8192, 256, 0, stream>>>(Wq, Wk, Wv, Wo, Er, x, ln_g, ln_b,
                                           wt, er_b, h);
  qkv_gemm<<<dim3(128, 24), 256, 0, stream>>>(h, wt, bq, bk, bv, q_ws, k_ws, vt_ws);
  attn_kernel<<<dim3(16, 64), 256, 0, stream>>>(q_ws, k_ws, vt_ws, er_b, o_ws);
  out_gemm<<<dim3(128, 8), 256, 0, stream>>>(o_ws, wt + 3 * 262144, bo, out);
}